// Round 17
// baseline (1138.120 us; speedup 1.0000x reference)
//
#include <hip/hip_runtime.h>

#define T_TOK 2048
#define HDIM  2048
#define FDIM  4096
#define NEXP  8

#define BM 128
#define BK 64
#define BKP 68
#define NT 256

typedef float f32x4 __attribute__((ext_vector_type(4)));
typedef float fvec4 __attribute__((ext_vector_type(4)));
typedef short s16x4 __attribute__((ext_vector_type(4)));
typedef short s16x8 __attribute__((ext_vector_type(8)));
typedef unsigned uint2v __attribute__((ext_vector_type(2)));

__device__ __forceinline__ short f2bf(float f) {
  union { float f; unsigned u; } c; c.f = f;
  unsigned r = c.u + 0x7FFFu + ((c.u >> 16) & 1u);
  return (short)(r >> 16);
}
__device__ __forceinline__ float bf2f(short h) {
  union { float f; unsigned u; } c; c.u = ((unsigned)(unsigned short)h) << 16;
  return c.f;
}
__device__ __forceinline__ unsigned cvtpk(float lo, float hi) {
  unsigned r;
  asm("v_cvt_pk_bf16_f32 %0, %1, %2" : "=v"(r) : "v"(lo), "v"(hi));
  return r;
}
template<int N> __device__ __forceinline__ void vmwait() {
  if constexpr (N == 0)       asm volatile("s_waitcnt vmcnt(0)" ::: "memory");
  else if constexpr (N == 4)  asm volatile("s_waitcnt vmcnt(4)" ::: "memory");
  else if constexpr (N == 8)  asm volatile("s_waitcnt vmcnt(8)" ::: "memory");
  else if constexpr (N == 12) asm volatile("s_waitcnt vmcnt(12)" ::: "memory");
  else if constexpr (N == 16) asm volatile("s_waitcnt vmcnt(16)" ::: "memory");
}

#define GLL16(gsrc, ldst) \
  __builtin_amdgcn_global_load_lds((const __attribute__((address_space(1))) void*)(gsrc), \
                                   (__attribute__((address_space(3))) void*)(ldst), 16, 0, 0)

// ---------------- merged weight convert+transpose (3 matrices, one launch) ----
__global__ __launch_bounds__(256) void tconv3_kernel(
    const float* __restrict__ sg, const float* __restrict__ su, const float* __restrict__ sd,
    short* __restrict__ sgT, short* __restrict__ suT, short* __restrict__ sdT)
{
  int z = blockIdx.z;
  const float* W; short* WT; int K, N;
  if (z == 0)      { W = sg; WT = sgT; K = HDIM; N = FDIM; }
  else if (z == 1) { W = su; WT = suT; K = HDIM; N = FDIM; }
  else             { W = sd; WT = sdT; K = FDIM; N = HDIM; }
  int n0 = blockIdx.x * 64, k0 = blockIdx.y * 64;
  if (n0 >= N || k0 >= K) return;
  __shared__ float tile[64][65];
  int t = threadIdx.x;
  int tc = t & 15, tr = t >> 4;
  #pragma unroll
  for (int i = 0; i < 4; i++) {
    int k = tr + i * 16;
    fvec4 v = *(const fvec4*)(W + (size_t)(k0 + k) * N + n0 + tc * 4);
    tile[k][tc * 4 + 0] = v.x; tile[k][tc * 4 + 1] = v.y;
    tile[k][tc * 4 + 2] = v.z; tile[k][tc * 4 + 3] = v.w;
  }
  __syncthreads();
  int n = t >> 2, ks = (t & 3) * 16;
  s16x8 o0, o1;
  #pragma unroll
  for (int j = 0; j < 8; j++) {
    o0[j] = f2bf(tile[ks + j][n]);
    o1[j] = f2bf(tile[ks + 8 + j][n]);
  }
  *(s16x8*)(WT + (size_t)(n0 + n) * K + k0 + ks) = o0;
  *(s16x8*)(WT + (size_t)(n0 + n) * K + k0 + ks + 8) = o1;
}

// ---------------- router: logits + top1 + sigmoid score + bf16 h ----------------
__global__ __launch_bounds__(256) void router_kernel(
    const float* __restrict__ h, const float* __restrict__ rw,
    float* __restrict__ logits, int* __restrict__ eid, float* __restrict__ score,
    short* __restrict__ hb)
{
  int tok  = blockIdx.x * 4 + (threadIdx.x >> 6);
  int lane = threadIdx.x & 63;
  float a[8] = {0.f,0.f,0.f,0.f,0.f,0.f,0.f,0.f};
  const float* hp = h + (size_t)tok * HDIM;
  short* hbp = hb + (size_t)tok * HDIM;
  for (int i0 = lane * 4; i0 < HDIM; i0 += 256) {
    fvec4 hv = *(const fvec4*)(hp + i0);
    s16x4 o = { f2bf(hv.x), f2bf(hv.y), f2bf(hv.z), f2bf(hv.w) };
    *(s16x4*)(hbp + i0) = o;
    #pragma unroll
    for (int j = 0; j < 4; j++) {
      const fvec4* wp = (const fvec4*)(rw + (size_t)(i0 + j) * NEXP);
      fvec4 w0 = wp[0], w1 = wp[1];
      float hv1 = hv[j];
      a[0] += hv1 * w0.x; a[1] += hv1 * w0.y; a[2] += hv1 * w0.z; a[3] += hv1 * w0.w;
      a[4] += hv1 * w1.x; a[5] += hv1 * w1.y; a[6] += hv1 * w1.z; a[7] += hv1 * w1.w;
    }
  }
  #pragma unroll
  for (int e = 0; e < 8; e++) {
    #pragma unroll
    for (int off = 32; off; off >>= 1)
      a[e] += __shfl_xor(a[e], off, 64);
  }
  if (lane == 0) {
    float best = a[0]; int bi = 0;
    #pragma unroll
    for (int e = 1; e < 8; e++) if (a[e] > best) { best = a[e]; bi = e; }
    #pragma unroll
    for (int e = 0; e < 8; e++) logits[(size_t)tok * NEXP + e] = a[e];
    eid[tok] = bi;
    score[tok] = 1.0f / (1.0f + __expf(-best));
  }
}

// ---------------- stable counting sort of tokens by expert ----------------
__global__ __launch_bounds__(512) void sort_kernel(
    const int* __restrict__ eid, int* __restrict__ perm, int* __restrict__ ofs)
{
  __shared__ int s_cnt[8];
  __shared__ int s_off[9];
  int w = threadIdx.x >> 6, lane = threadIdx.x & 63;
  int cnt = 0;
  for (int b = 0; b < T_TOK; b += 64) {
    int id = eid[b + lane];
    unsigned long long m = __ballot(id == w);
    cnt += __popcll(m);
  }
  if (lane == 0) s_cnt[w] = cnt;
  __syncthreads();
  if (threadIdx.x == 0) {
    int o = 0;
    for (int e = 0; e < 8; e++) { s_off[e] = o; o += s_cnt[e]; }
    s_off[8] = o;
    for (int e = 0; e < 9; e++) ofs[e] = s_off[e];
  }
  __syncthreads();
  int pos = s_off[w];
  for (int b = 0; b < T_TOK; b += 64) {
    int tokidx = b + lane;
    int id = eid[tokidx];
    unsigned long long m = __ballot(id == w);
    if (id == w) {
      int p = pos + __popcll(m & ((1ull << lane) - 1ull));
      perm[p] = tokidx;
    }
    pos += __popcll(m);
  }
}

// ---------------- build permuted+scaled x from bf16 h ----------------
__global__ __launch_bounds__(256) void build_kernel(
    const short* __restrict__ hb, const float* __restrict__ score,
    const int* __restrict__ perm, short* __restrict__ xp)
{
  int row = blockIdx.x;
  int tok = perm[row];
  float s = score[tok];
  const s16x8* src = (const s16x8*)(hb + (size_t)tok * HDIM);
  int j = threadIdx.x;   // HDIM/8 == 256 == blockDim
  s16x8 v = src[j];
  s16x8 o;
  #pragma unroll
  for (int i = 0; i < 8; i++) o[i] = f2bf(bf2f(v[i]) * s);
  *(s16x8*)(xp + (size_t)row * HDIM + j * 8) = o;
}

// ---------------- unified MoE GEMM ----------------
// MODE 0: fused gate-up 2-pass (tiles [0,KT)=gate, [KT,2KT)=up); epi silu(g)*u -> bf16
// MODE 1: plain fp32 store
// MODE 2: fp32 accumulate via perm rows
// B16=true : A and B bf16, both global_load_lds staged, 2-phase dbuf (R6-proven path).
//            Wave tile 64x64 (2x2 waves).
// B16=false: B fp32 [K,N] reg-staged + cvt_pk into LDS, DEEP pipeline (distance-2 B,
//            counted vmcnt). A read DIRECTLY global->VGPR (L2-resident xp/act_rt) —
//            no sA, LDS 35KB -> 4 blocks/CU. Wave tile 32x64 (4x1 waves).
template<int MODE, bool B16, int BN_, int OCC>
__global__ __launch_bounds__(NT, OCC) void moe_gemm(
    const short* __restrict__ A, int lda,
    const void* __restrict__ B0v, const void* __restrict__ B1v,
    long long bstride, int ldb,
    void* __restrict__ Cv, int ldc,
    const int* __restrict__ gofs, int mt_per_g, int K,
    const int* __restrict__ perm)
{
  constexpr int MREP_ = B16 ? 4 : 2;
  constexpr int NREP_ = B16 ? BN_ / 32 : BN_ / 16;
  constexpr int CQ   = BN_ / 4;                // fp32-stage col quads
  constexpr int UPT  = (CQ * (BK / 4)) / NT;   // fp32-stage units per thread
  constexpr int NB   = 4 * UPT;                // B vmem loads per issue
  constexpr int BSTR = B16 ? BK : BKP;
  constexpr int SASZ = B16 ? 2 * BM * BK : 2;

  __shared__ short sA[SASZ];
  __shared__ short sB[2][BN_ * BSTR];

  int g  = blockIdx.y / mt_per_g;
  int mt = blockIdx.y % mt_per_g;
  int r0 = 0, r1 = T_TOK;
  if (gofs) { r0 = gofs[g]; r1 = gofs[g+1]; }
  int row0 = r0 + mt * BM;
  if (row0 >= r1) return;
  int rows = r1 - row0; if (rows > BM) rows = BM;
  int n0 = blockIdx.x * BN_;

  const float* Bg32 = nullptr; const float* Bu32 = nullptr;
  const short* Bg16 = nullptr; const short* Bu16 = nullptr;
  if constexpr (B16) {
    Bg16 = (const short*)B0v + (size_t)g * (size_t)bstride;
    if (MODE == 0) Bu16 = (const short*)B1v + (size_t)g * (size_t)bstride;
  } else {
    Bg32 = (const float*)B0v + (size_t)g * (size_t)bstride;
    if (MODE == 0) Bu32 = (const float*)B1v + (size_t)g * (size_t)bstride;
  }

  int tid = threadIdx.x;
  int lane = tid & 63, w = tid >> 6;
  int wr = B16 ? (w >> 1) * 64 : w * 32;
  int wc = B16 ? (w & 1) * (BN_ / 2) : 0;
  int l16 = lane & 15, lh = lane >> 4;

  // B16: gll stage lane mapping (A and B)
  int arow_in = lane >> 3;
  int akoff   = (((lane & 7) ^ arow_in) << 3);   // pre-swizzled k offset (shorts)
  const short* aBase[4];
  if constexpr (B16) {
    #pragma unroll
    for (int i = 0; i < 4; i++) {
      int row = (w * 4 + i) * 8 + arow_in;
      int growc = row0 + row; if (growc > T_TOK - 1) growc = T_TOK - 1;
      aBase[i] = A + (size_t)growc * lda + akoff;
    }
  }
  // !B16: per-wave A row base pointers (direct global reads)
  const short* aRow[2];
  if constexpr (!B16) {
    #pragma unroll
    for (int m = 0; m < 2; m++) {
      int rr = row0 + wr + m * 16 + l16;
      if (rr > T_TOK - 1) rr = T_TOK - 1;
      aRow[m] = A + (size_t)rr * lda;
    }
  }

  const int KT = K / BK;
  const int NTILES = (MODE == 0) ? 2 * KT : KT;

  f32x4 zero4 = {0.f, 0.f, 0.f, 0.f};
  f32x4 acc[MREP_][NREP_];
  #pragma unroll
  for (int m = 0; m < MREP_; m++)
    #pragma unroll
    for (int n = 0; n < NREP_; n++) acc[m][n] = zero4;
  s16x4 sgate[MODE == 0 ? MREP_ : 1][MODE == 0 ? NREP_ : 1];

  auto issueA16 = [&](int tt, int bb) {
    if constexpr (B16) {
      int k0 = (tt & (KT - 1)) * BK;
      #pragma unroll
      for (int i = 0; i < 4; i++)
        GLL16(aBase[i] + k0, &sA[bb * BM * BK + (w * 4 + i) * 8 * BK]);
    }
  };
  auto issueB16 = [&](int tt, int bb) {
    if constexpr (B16) {
      int k0 = (tt & (KT - 1)) * BK;
      const short* BTp = (MODE == 0 && tt >= KT) ? Bu16 : Bg16;
      #pragma unroll
      for (int i = 0; i < BN_ / 32; i++) {
        int rbase = (w * (BN_ / 32) + i) * 8;
        const short* src = BTp + (size_t)(n0 + rbase + arow_in) * ldb + k0 + akoff;
        GLL16(src, &sB[bb][rbase * BSTR]);
      }
    }
  };
  auto issueB32 = [&](int tt, fvec4 (&br)[UPT][4]) {
    int k0 = (tt & (KT - 1)) * BK;
    const float* Bp = (MODE == 0 && tt >= KT) ? Bu32 : Bg32;
    #pragma unroll
    for (int u = 0; u < UPT; u++) {
      int unit = tid + u * NT;
      int bcg = unit % CQ, bkb = unit / CQ;
      const float* bp = Bp + (size_t)(k0 + bkb * 4) * ldb + n0 + bcg * 4;
      #pragma unroll
      for (int r = 0; r < 4; r++)
        br[u][r] = *(const fvec4*)(bp + (size_t)r * ldb);
    }
  };
  auto writeB32 = [&](fvec4 (&br)[UPT][4], int bb) {
    #pragma unroll
    for (int u = 0; u < UPT; u++) {
      int unit = tid + u * NT;
      int bcg = unit % CQ, bkb = unit / CQ;
      #pragma unroll
      for (int i2 = 0; i2 < 4; i2++) {
        uint2v o;
        o.x = cvtpk(br[u][0][i2], br[u][1][i2]);
        o.y = cvtpk(br[u][2][i2], br[u][3][i2]);
        *(uint2v*)(&sB[bb][(bcg * 4 + i2) * BSTR + bkb * 4]) = o;
      }
    }
  };
  auto siluGate = [&]() {
    #pragma unroll
    for (int m = 0; m < MREP_; m++)
      #pragma unroll
      for (int n = 0; n < NREP_; n++) {
        #pragma unroll
        for (int r = 0; r < 4; r++) {
          float gv = acc[m][n][r];
          sgate[m][n][r] = f2bf(gv / (1.0f + __expf(-gv)));
        }
        acc[m][n] = zero4;
      }
  };
  // B16 compute (sA + sB, wave tile 64x64) — R6-proven
  auto compute16 = [&](int bb) {
    if constexpr (B16) {
      const short* sa = sA + bb * BM * BK;
      const short* sb = sB[bb];
      __builtin_amdgcn_s_setprio(1);
      #pragma unroll
      for (int kk = 0; kk < BK; kk += 32) {
        s16x8 aF[MREP_], bF[NREP_];
        #pragma unroll
        for (int m = 0; m < MREP_; m++) {
          int row = wr + m * 16 + l16;
          int slot = ((kk >> 3) + lh) ^ (row & 7);
          aF[m] = *(const s16x8*)(&sa[row * BK + slot * 8]);
        }
        #pragma unroll
        for (int n = 0; n < NREP_; n++) {
          int col = wc + n * 16 + l16;
          int slot = ((kk >> 3) + lh) ^ (col & 7);
          bF[n] = *(const s16x8*)(&sb[col * BSTR + slot * 8]);
        }
        #pragma unroll
        for (int m = 0; m < MREP_; m++)
          #pragma unroll
          for (int n = 0; n < NREP_; n++)
            acc[m][n] = __builtin_amdgcn_mfma_f32_16x16x32_bf16(aF[m], bF[n], acc[m][n], 0, 0, 0);
      }
      __builtin_amdgcn_s_setprio(0);
    }
  };
  // !B16: A-frag loads for one K-tile (issue BEFORE B-prefetch: oldest in vmcnt order)
  auto loadA = [&](int tt, s16x8 (&aF)[2][2]) {
    int k0 = (tt & (KT - 1)) * BK;
    #pragma unroll
    for (int kh = 0; kh < 2; kh++)
      #pragma unroll
      for (int m = 0; m < 2; m++)
        aF[kh][m] = *(const s16x8*)(aRow[m] + k0 + kh * 32 + lh * 8);
  };
  auto computeR = [&](int bb, s16x8 (&aF)[2][2]) {
    const short* sb = sB[bb];
    __builtin_amdgcn_s_setprio(1);
    #pragma unroll
    for (int kh = 0; kh < 2; kh++) {
      s16x8 bF[NREP_];
      #pragma unroll
      for (int n = 0; n < NREP_; n++) {
        int col = n * 16 + l16;
        int kb = kh * 32 + lh * 8;
        s16x4 lo = *(const s16x4*)(&sb[col * BSTR + kb]);
        s16x4 hi = *(const s16x4*)(&sb[col * BSTR + kb + 4]);
        bF[n] = __builtin_shufflevector(lo, hi, 0, 1, 2, 3, 4, 5, 6, 7);
      }
      #pragma unroll
      for (int m = 0; m < 2; m++)
        #pragma unroll
        for (int n = 0; n < NREP_; n++)
          acc[m][n] = __builtin_amdgcn_mfma_f32_16x16x32_bf16(aF[kh][m], bF[n], acc[m][n], 0, 0, 0);
    }
    __builtin_amdgcn_s_setprio(0);
  };

  if constexpr (B16) {
    // ---- 2-phase dbuf (R6-proven) ----
    issueA16(0, 0);
    issueB16(0, 0);
    asm volatile("s_waitcnt vmcnt(0)" ::: "memory");
    asm volatile("s_waitcnt lgkmcnt(0)" ::: "memory");
    __builtin_amdgcn_s_barrier();
    int buf = 0;
    for (int tt = 0; tt < NTILES; ++tt) {
      bool has_next = (tt + 1 < NTILES);
      if (has_next) { issueA16(tt + 1, buf ^ 1); issueB16(tt + 1, buf ^ 1); }
      compute16(buf);
      if (MODE == 0 && tt == KT - 1) siluGate();
      if (has_next) {
        asm volatile("s_waitcnt vmcnt(0)" ::: "memory");
        asm volatile("s_waitcnt lgkmcnt(0)" ::: "memory");
        __builtin_amdgcn_s_barrier();
        buf ^= 1;
      }
    }
  } else {
    // ---- deep pipeline: distance-2 B loads, counted vmcnt; A direct from L2 ----
    fvec4 BrA[UPT][4], BrB[UPT][4];
    issueB32(0, BrA);
    asm volatile("s_waitcnt vmcnt(0)" ::: "memory");
    writeB32(BrA, 0);
    issueB32(1, BrB);
    asm volatile("s_waitcnt lgkmcnt(0)" ::: "memory");
    __builtin_amdgcn_s_barrier();
    int buf = 0;
    // NTILES is even in all !B16 uses; body unrolled 2x for reg ping-pong
    for (int tt = 0; tt < NTILES; tt += 2) {
      // even phase: BrB holds B(tt+1)
      {
        bool hn2 = (tt + 2 < NTILES);
        s16x8 aF[2][2];
        loadA(tt, aF);                    // oldest vmem: MFMA waits touch only these
        if (hn2) issueB32(tt + 2, BrA);
        computeR(buf, aF);
        if (MODE == 0 && tt == KT - 1) siluGate();
        if (hn2) vmwait<NB>(); else vmwait<0>();
        writeB32(BrB, buf ^ 1);
        asm volatile("s_waitcnt lgkmcnt(0)" ::: "memory");
        __builtin_amdgcn_s_barrier();
        buf ^= 1;
      }
      // odd phase: BrA holds B(tt+2)
      {
        int t1 = tt + 1;
        bool hn  = (t1 + 1 < NTILES);
        bool hn2 = (t1 + 2 < NTILES);
        s16x8 aF[2][2];
        if (hn) {
          loadA(t1, aF);
          if (hn2) issueB32(t1 + 2, BrB);
          computeR(buf, aF);
          if (MODE == 0 && t1 == KT - 1) siluGate();
          if (hn2) vmwait<NB>(); else vmwait<0>();
          writeB32(BrA, buf ^ 1);
          asm volatile("s_waitcnt lgkmcnt(0)" ::: "memory");
          __builtin_amdgcn_s_barrier();
          buf ^= 1;
        } else {
          loadA(t1, aF);
          computeR(buf, aF);              // last tile
        }
      }
    }
  }

  // ---- epilogue ----
  #pragma unroll
  for (int m = 0; m < MREP_; m++) {
    #pragma unroll
    for (int r = 0; r < 4; r++) {
      int lr = wr + m * 16 + lh * 4 + r;
      if (lr >= rows) continue;
      size_t grow = (MODE == 2) ? (size_t)perm[row0 + lr] : (size_t)(row0 + lr);
      size_t base = grow * (size_t)ldc + n0;
      #pragma unroll
      for (int n = 0; n < NREP_; n++) {
        int col = wc + n * 16 + l16;
        float v = acc[m][n][r];
        if constexpr (MODE == 0) {
          ((short*)Cv)[base + col] = f2bf(bf2f(sgate[m][n][r]) * v);
        } else if constexpr (MODE == 1) {
          ((float*)Cv)[base + col] = v;
        } else {
          ((float*)Cv)[base + col] += v;
        }
      }
    }
  }
}

// ---------------- launch ----------------
extern "C" void kernel_launch(void* const* d_in, const int* in_sizes, int n_in,
                              void* d_out, int out_size, void* d_ws, size_t ws_size,
                              hipStream_t stream)
{
  const float* h   = (const float*)d_in[0];
  const float* rw  = (const float*)d_in[1];
  const float* gup = (const float*)d_in[2];
  const float* dwn = (const float*)d_in[3];
  const float* sg  = (const float*)d_in[4];
  const float* su  = (const float*)d_in[5];
  const float* sd  = (const float*)d_in[6];
  float* out0   = (float*)d_out;                       // [T, H]
  float* logits = out0 + (size_t)T_TOK * HDIM;         // [T, E]

  char* ws = (char*)d_ws;
  int*   eid    = (int*)ws;                  // 2048 ints
  float* score  = (float*)(ws + 8192);       // 2048 floats
  int*   perm   = (int*)(ws + 16384);        // 2048 ints
  int*   ofs    = (int*)(ws + 24576);        // 9 ints
  short* hb     = (short*)(ws + 32768);                 // [T, H] bf16
  short* xp     = hb  + (size_t)T_TOK * HDIM;           // [T, H] bf16 (perm+scaled)
  short* act_sh = xp  + (size_t)T_TOK * HDIM;           // [T, F] bf16
  short* act_rt = act_sh + (size_t)T_TOK * FDIM;        // [T, F] bf16 (perm space)
  short* sgT    = act_rt + (size_t)T_TOK * FDIM + 8192; // [F, H] bf16 (transposed)
  short* suT    = sgT + (size_t)FDIM * HDIM;            // [F, H] bf16
  short* sdT    = suT + (size_t)FDIM * HDIM;            // [H, F] bf16

  // shared weight conversions (one launch)
  tconv3_kernel<<<dim3(64, 64, 3), 256, 0, stream>>>(sg, su, sd, sgT, suT, sdT);

  router_kernel<<<T_TOK/4, 256, 0, stream>>>(h, rw, logits, eid, score, hb);
  sort_kernel<<<1, 512, 0, stream>>>(eid, perm, ofs);
  build_kernel<<<T_TOK, 256, 0, stream>>>(hb, score, perm, xp);

  const int MT = T_TOK / 128;   // 16
  const int MTR = 4;            // routed mt cap: 512 rows/expert (mean 256±15)

  // shared gate+up fused -> act_sh   (all-bf16, 128x128x64, R6-proven)
  dim3 g_gu_sh(FDIM / 128, MT);
  moe_gemm<0, true, 128, 2><<<g_gu_sh, 256, 0, stream>>>(
      hb, HDIM, sgT, suT, 0, HDIM, act_sh, FDIM, nullptr, MT, HDIM, nullptr);
  // shared down -> out0 (store)      (all-bf16, 128x128x64, R6-proven)
  dim3 g_dn_sh(HDIM / 128, MT);
  moe_gemm<1, true, 128, 2><<<g_dn_sh, 256, 0, stream>>>(
      act_sh, FDIM, sdT, nullptr, 0, FDIM, out0, HDIM, nullptr, MT, FDIM, nullptr);
  // routed gate+up fused (grouped) -> act_rt  (fp32-B deep pipeline, A direct, OCC=4)
  dim3 g_gu_rt(FDIM / 64, NEXP * MTR);
  moe_gemm<0, false, 64, 4><<<g_gu_rt, 256, 0, stream>>>(
      xp, HDIM, gup, gup + FDIM, (long long)HDIM * 2 * FDIM, 2 * FDIM,
      act_rt, FDIM, ofs, MTR, HDIM, nullptr);
  // routed down (grouped, accumulate into out0)  (fp32-B deep pipeline, A direct, OCC=4)
  dim3 g_dn_rt(HDIM / 64, NEXP * MTR);
  moe_gemm<2, false, 64, 4><<<g_dn_rt, 256, 0, stream>>>(
      act_rt, FDIM, dwn, nullptr, (long long)FDIM * HDIM, HDIM,
      out0, HDIM, ofs, MTR, FDIM, perm);
}

// Round 18
// 523.672 us; speedup vs baseline: 2.1733x; 2.1733x over previous
//
#include <hip/hip_runtime.h>

#define T_TOK 2048
#define HDIM  2048
#define FDIM  4096
#define NEXP  8

#define BM 128
#define BK 64
#define NT 256

typedef float f32x4 __attribute__((ext_vector_type(4)));
typedef float fvec4 __attribute__((ext_vector_type(4)));
typedef short s16x4 __attribute__((ext_vector_type(4)));
typedef short s16x8 __attribute__((ext_vector_type(8)));
typedef unsigned uint2v __attribute__((ext_vector_type(2)));

__device__ __forceinline__ short f2bf(float f) {
  union { float f; unsigned u; } c; c.f = f;
  unsigned r = c.u + 0x7FFFu + ((c.u >> 16) & 1u);
  return (short)(r >> 16);
}
__device__ __forceinline__ float bf2f(short h) {
  union { float f; unsigned u; } c; c.u = ((unsigned)(unsigned short)h) << 16;
  return c.f;
}
__device__ __forceinline__ unsigned cvtpk(float lo, float hi) {
  unsigned r;
  asm("v_cvt_pk_bf16_f32 %0, %1, %2" : "=v"(r) : "v"(lo), "v"(hi));
  return r;
}
template<int N> __device__ __forceinline__ void vmwait() {
  if constexpr (N == 0)       asm volatile("s_waitcnt vmcnt(0)" ::: "memory");
  else if constexpr (N == 4)  asm volatile("s_waitcnt vmcnt(4)" ::: "memory");
  else if constexpr (N == 8)  asm volatile("s_waitcnt vmcnt(8)" ::: "memory");
  else if constexpr (N == 12) asm volatile("s_waitcnt vmcnt(12)" ::: "memory");
  else if constexpr (N == 16) asm volatile("s_waitcnt vmcnt(16)" ::: "memory");
}

#define GLL16(gsrc, ldst) \
  __builtin_amdgcn_global_load_lds((const __attribute__((address_space(1))) void*)(gsrc), \
                                   (__attribute__((address_space(3))) void*)(ldst), 16, 0, 0)

// ---------------- merged weight convert+transpose (3 matrices, one launch) ----
__global__ __launch_bounds__(256) void tconv3_kernel(
    const float* __restrict__ sg, const float* __restrict__ su, const float* __restrict__ sd,
    short* __restrict__ sgT, short* __restrict__ suT, short* __restrict__ sdT)
{
  int z = blockIdx.z;
  const float* W; short* WT; int K, N;
  if (z == 0)      { W = sg; WT = sgT; K = HDIM; N = FDIM; }
  else if (z == 1) { W = su; WT = suT; K = HDIM; N = FDIM; }
  else             { W = sd; WT = sdT; K = FDIM; N = HDIM; }
  int n0 = blockIdx.x * 64, k0 = blockIdx.y * 64;
  if (n0 >= N || k0 >= K) return;
  __shared__ float tile[64][65];
  int t = threadIdx.x;
  int tc = t & 15, tr = t >> 4;
  #pragma unroll
  for (int i = 0; i < 4; i++) {
    int k = tr + i * 16;
    fvec4 v = *(const fvec4*)(W + (size_t)(k0 + k) * N + n0 + tc * 4);
    tile[k][tc * 4 + 0] = v.x; tile[k][tc * 4 + 1] = v.y;
    tile[k][tc * 4 + 2] = v.z; tile[k][tc * 4 + 3] = v.w;
  }
  __syncthreads();
  int n = t >> 2, ks = (t & 3) * 16;
  s16x8 o0, o1;
  #pragma unroll
  for (int j = 0; j < 8; j++) {
    o0[j] = f2bf(tile[ks + j][n]);
    o1[j] = f2bf(tile[ks + 8 + j][n]);
  }
  *(s16x8*)(WT + (size_t)(n0 + n) * K + k0 + ks) = o0;
  *(s16x8*)(WT + (size_t)(n0 + n) * K + k0 + ks + 8) = o1;
}

// ---------------- router: logits + top1 + sigmoid score + bf16 h ----------------
__global__ __launch_bounds__(256) void router_kernel(
    const float* __restrict__ h, const float* __restrict__ rw,
    float* __restrict__ logits, int* __restrict__ eid, float* __restrict__ score,
    short* __restrict__ hb)
{
  int tok  = blockIdx.x * 4 + (threadIdx.x >> 6);
  int lane = threadIdx.x & 63;
  float a[8] = {0.f,0.f,0.f,0.f,0.f,0.f,0.f,0.f};
  const float* hp = h + (size_t)tok * HDIM;
  short* hbp = hb + (size_t)tok * HDIM;
  for (int i0 = lane * 4; i0 < HDIM; i0 += 256) {
    fvec4 hv = *(const fvec4*)(hp + i0);
    s16x4 o = { f2bf(hv.x), f2bf(hv.y), f2bf(hv.z), f2bf(hv.w) };
    *(s16x4*)(hbp + i0) = o;
    #pragma unroll
    for (int j = 0; j < 4; j++) {
      const fvec4* wp = (const fvec4*)(rw + (size_t)(i0 + j) * NEXP);
      fvec4 w0 = wp[0], w1 = wp[1];
      float hv1 = hv[j];
      a[0] += hv1 * w0.x; a[1] += hv1 * w0.y; a[2] += hv1 * w0.z; a[3] += hv1 * w0.w;
      a[4] += hv1 * w1.x; a[5] += hv1 * w1.y; a[6] += hv1 * w1.z; a[7] += hv1 * w1.w;
    }
  }
  #pragma unroll
  for (int e = 0; e < 8; e++) {
    #pragma unroll
    for (int off = 32; off; off >>= 1)
      a[e] += __shfl_xor(a[e], off, 64);
  }
  if (lane == 0) {
    float best = a[0]; int bi = 0;
    #pragma unroll
    for (int e = 1; e < 8; e++) if (a[e] > best) { best = a[e]; bi = e; }
    #pragma unroll
    for (int e = 0; e < 8; e++) logits[(size_t)tok * NEXP + e] = a[e];
    eid[tok] = bi;
    score[tok] = 1.0f / (1.0f + __expf(-best));
  }
}

// ---------------- stable counting sort of tokens by expert ----------------
__global__ __launch_bounds__(512) void sort_kernel(
    const int* __restrict__ eid, int* __restrict__ perm, int* __restrict__ ofs)
{
  __shared__ int s_cnt[8];
  __shared__ int s_off[9];
  int w = threadIdx.x >> 6, lane = threadIdx.x & 63;
  int cnt = 0;
  for (int b = 0; b < T_TOK; b += 64) {
    int id = eid[b + lane];
    unsigned long long m = __ballot(id == w);
    cnt += __popcll(m);
  }
  if (lane == 0) s_cnt[w] = cnt;
  __syncthreads();
  if (threadIdx.x == 0) {
    int o = 0;
    for (int e = 0; e < 8; e++) { s_off[e] = o; o += s_cnt[e]; }
    s_off[8] = o;
    for (int e = 0; e < 9; e++) ofs[e] = s_off[e];
  }
  __syncthreads();
  int pos = s_off[w];
  for (int b = 0; b < T_TOK; b += 64) {
    int tokidx = b + lane;
    int id = eid[tokidx];
    unsigned long long m = __ballot(id == w);
    if (id == w) {
      int p = pos + __popcll(m & ((1ull << lane) - 1ull));
      perm[p] = tokidx;
    }
    pos += __popcll(m);
  }
}

// ---------------- build permuted+scaled x from bf16 h ----------------
__global__ __launch_bounds__(256) void build_kernel(
    const short* __restrict__ hb, const float* __restrict__ score,
    const int* __restrict__ perm, short* __restrict__ xp)
{
  int row = blockIdx.x;
  int tok = perm[row];
  float s = score[tok];
  const s16x8* src = (const s16x8*)(hb + (size_t)tok * HDIM);
  int j = threadIdx.x;   // HDIM/8 == 256 == blockDim
  s16x8 v = src[j];
  s16x8 o;
  #pragma unroll
  for (int i = 0; i < 8; i++) o[i] = f2bf(bf2f(v[i]) * s);
  *(s16x8*)(xp + (size_t)row * HDIM + j * 8) = o;
}

// ---------------- unified MoE GEMM ----------------
// MODE 0: fused gate-up 2-pass (tiles [0,KT)=gate, [KT,2KT)=up); epi silu(g)*u -> bf16
// MODE 1: plain fp32 store
// MODE 2: fp32 accumulate via perm rows
// B16=true : B bf16 [N,K], global_load_lds staged, 2-phase dbuf (R6-proven path).
// B16=false: B fp32 [K,N], reg-staged + cvt_pk, DEEP pipeline (distance-2 B loads,
//            counted vmcnt — never drains to 0 in steady state).
template<int MODE, bool B16, int BN_, int OCC>
__global__ __launch_bounds__(NT, OCC) void moe_gemm(
    const short* __restrict__ A, int lda,
    const void* __restrict__ B0v, const void* __restrict__ B1v,
    long long bstride, int ldb,
    void* __restrict__ Cv, int ldc,
    const int* __restrict__ gofs, int mt_per_g, int K,
    const int* __restrict__ perm)
{
  constexpr int NREP = BN_ / 32;          // 16-col frags per wave
  constexpr int CQ   = BN_ / 4;           // fp32-stage col quads
  constexpr int UPT  = (CQ * (BK / 4)) / NT;   // fp32-stage units per thread
  constexpr int NB   = 4 * UPT;           // B vmem loads per issue
  constexpr int BSTR = B16 ? BK : (BK + 4);

  __shared__ short sA[2][BM * BK];
  __shared__ short sB[2][BN_ * BSTR];

  int g  = blockIdx.y / mt_per_g;
  int mt = blockIdx.y % mt_per_g;
  int r0 = 0, r1 = T_TOK;
  if (gofs) { r0 = gofs[g]; r1 = gofs[g+1]; }
  int row0 = r0 + mt * BM;
  if (row0 >= r1) return;
  int rows = r1 - row0; if (rows > BM) rows = BM;
  int n0 = blockIdx.x * BN_;

  const float* Bg32 = nullptr; const float* Bu32 = nullptr;
  const short* Bg16 = nullptr; const short* Bu16 = nullptr;
  if constexpr (B16) {
    Bg16 = (const short*)B0v + (size_t)g * (size_t)bstride;
    if (MODE == 0) Bu16 = (const short*)B1v + (size_t)g * (size_t)bstride;
  } else {
    Bg32 = (const float*)B0v + (size_t)g * (size_t)bstride;
    if (MODE == 0) Bu32 = (const float*)B1v + (size_t)g * (size_t)bstride;
  }

  int tid = threadIdx.x;
  int lane = tid & 63, w = tid >> 6;
  int wr = (w >> 1) * 64;
  int wc = (w & 1) * (BN_ / 2);
  int l16 = lane & 15, lh = lane >> 4;

  // gll stage lane mapping (shared by A and B16-B)
  int arow_in = lane >> 3;
  int akoff   = (((lane & 7) ^ arow_in) << 3);   // pre-swizzled k offset (shorts)
  const short* aBase[4];
  #pragma unroll
  for (int i = 0; i < 4; i++) {
    int row = (w * 4 + i) * 8 + arow_in;
    int growc = row0 + row; if (growc > T_TOK - 1) growc = T_TOK - 1;
    aBase[i] = A + (size_t)growc * lda + akoff;
  }

  const int KT = K / BK;
  const int NTILES = (MODE == 0) ? 2 * KT : KT;

  f32x4 zero4 = {0.f, 0.f, 0.f, 0.f};
  f32x4 acc[4][NREP];
  #pragma unroll
  for (int m = 0; m < 4; m++)
    #pragma unroll
    for (int n = 0; n < NREP; n++) acc[m][n] = zero4;
  s16x4 sgate[MODE == 0 ? 4 : 1][MODE == 0 ? NREP : 1];

  auto issueA = [&](int tt, int bb) {
    int k0 = (tt & (KT - 1)) * BK;
    #pragma unroll
    for (int i = 0; i < 4; i++)
      GLL16(aBase[i] + k0, &sA[bb][(w * 4 + i) * 8 * BK]);
  };
  auto issueB16 = [&](int tt, int bb) {
    int k0 = (tt & (KT - 1)) * BK;
    const short* BTp = (MODE == 0 && tt >= KT) ? Bu16 : Bg16;
    #pragma unroll
    for (int i = 0; i < BN_ / 32; i++) {
      int rbase = (w * (BN_ / 32) + i) * 8;
      const short* src = BTp + (size_t)(n0 + rbase + arow_in) * ldb + k0 + akoff;
      GLL16(src, &sB[bb][rbase * BSTR]);
    }
  };
  auto issueB32 = [&](int tt, fvec4 (&br)[UPT][4]) {
    int k0 = (tt & (KT - 1)) * BK;
    const float* Bp = (MODE == 0 && tt >= KT) ? Bu32 : Bg32;
    #pragma unroll
    for (int u = 0; u < UPT; u++) {
      int unit = tid + u * NT;
      int bcg = unit % CQ, bkb = unit / CQ;
      const float* bp = Bp + (size_t)(k0 + bkb * 4) * ldb + n0 + bcg * 4;
      #pragma unroll
      for (int r = 0; r < 4; r++)
        br[u][r] = *(const fvec4*)(bp + (size_t)r * ldb);
    }
  };
  auto writeB32 = [&](fvec4 (&br)[UPT][4], int bb) {
    #pragma unroll
    for (int u = 0; u < UPT; u++) {
      int unit = tid + u * NT;
      int bcg = unit % CQ, bkb = unit / CQ;
      #pragma unroll
      for (int i2 = 0; i2 < 4; i2++) {
        uint2v o;
        o.x = cvtpk(br[u][0][i2], br[u][1][i2]);
        o.y = cvtpk(br[u][2][i2], br[u][3][i2]);
        *(uint2v*)(&sB[bb][(bcg * 4 + i2) * BSTR + bkb * 4]) = o;
      }
    }
  };
  auto siluGate = [&]() {
    #pragma unroll
    for (int m = 0; m < 4; m++)
      #pragma unroll
      for (int n = 0; n < NREP; n++) {
        #pragma unroll
        for (int r = 0; r < 4; r++) {
          float gv = acc[m][n][r];
          sgate[m][n][r] = f2bf(gv / (1.0f + __expf(-gv)));
        }
        acc[m][n] = zero4;
      }
  };
  auto compute = [&](int bb) {
    const short* sa = sA[bb];
    const short* sb = sB[bb];
    __builtin_amdgcn_s_setprio(1);
    #pragma unroll
    for (int kk = 0; kk < BK; kk += 32) {
      s16x8 aF[4], bF[NREP];
      #pragma unroll
      for (int m = 0; m < 4; m++) {
        int row = wr + m * 16 + l16;
        int slot = ((kk >> 3) + lh) ^ (row & 7);
        aF[m] = *(const s16x8*)(&sa[row * BK + slot * 8]);
      }
      #pragma unroll
      for (int n = 0; n < NREP; n++) {
        int col = wc + n * 16 + l16;
        if constexpr (B16) {
          int slot = ((kk >> 3) + lh) ^ (col & 7);
          bF[n] = *(const s16x8*)(&sb[col * BSTR + slot * 8]);
        } else {
          int kb = kk + lh * 8;
          s16x4 lo = *(const s16x4*)(&sb[col * BSTR + kb]);
          s16x4 hi = *(const s16x4*)(&sb[col * BSTR + kb + 4]);
          bF[n] = __builtin_shufflevector(lo, hi, 0, 1, 2, 3, 4, 5, 6, 7);
        }
      }
      #pragma unroll
      for (int m = 0; m < 4; m++)
        #pragma unroll
        for (int n = 0; n < NREP; n++)
          acc[m][n] = __builtin_amdgcn_mfma_f32_16x16x32_bf16(aF[m], bF[n], acc[m][n], 0, 0, 0);
    }
    __builtin_amdgcn_s_setprio(0);
  };

  if constexpr (B16) {
    // ---- 2-phase dbuf (R6-proven) ----
    issueA(0, 0);
    issueB16(0, 0);
    asm volatile("s_waitcnt vmcnt(0)" ::: "memory");
    asm volatile("s_waitcnt lgkmcnt(0)" ::: "memory");
    __builtin_amdgcn_s_barrier();
    int buf = 0;
    for (int tt = 0; tt < NTILES; ++tt) {
      bool has_next = (tt + 1 < NTILES);
      if (has_next) { issueA(tt + 1, buf ^ 1); issueB16(tt + 1, buf ^ 1); }
      compute(buf);
      if (MODE == 0 && tt == KT - 1) siluGate();
      if (has_next) {
        asm volatile("s_waitcnt vmcnt(0)" ::: "memory");
        asm volatile("s_waitcnt lgkmcnt(0)" ::: "memory");
        __builtin_amdgcn_s_barrier();
        buf ^= 1;
      }
    }
  } else {
    // ---- deep pipeline: distance-2 B loads, counted vmcnt ----
    fvec4 BrA[UPT][4], BrB[UPT][4];
    issueA(0, 0);
    issueB32(0, BrA);
    asm volatile("s_waitcnt vmcnt(0)" ::: "memory");
    writeB32(BrA, 0);
    issueB32(1, BrB);
    asm volatile("s_waitcnt lgkmcnt(0)" ::: "memory");
    __builtin_amdgcn_s_barrier();
    int buf = 0;
    // NTILES is even in all !B16 uses; body unrolled 2x for reg ping-pong
    for (int tt = 0; tt < NTILES; tt += 2) {
      // even phase: BrB holds B(tt+1)
      {
        bool hn2 = (tt + 2 < NTILES);
        issueA(tt + 1, buf ^ 1);
        if (hn2) issueB32(tt + 2, BrA);
        compute(buf);
        if (MODE == 0 && tt == KT - 1) siluGate();
        if (hn2) vmwait<4 + NB>(); else vmwait<4>();
        writeB32(BrB, buf ^ 1);
        if (hn2) vmwait<NB>(); else vmwait<0>();
        asm volatile("s_waitcnt lgkmcnt(0)" ::: "memory");
        __builtin_amdgcn_s_barrier();
        buf ^= 1;
      }
      // odd phase: BrA holds B(tt+2)
      {
        int t1 = tt + 1;
        bool hn  = (t1 + 1 < NTILES);
        bool hn2 = (t1 + 2 < NTILES);
        if (hn) {
          issueA(t1 + 1, buf ^ 1);
          if (hn2) issueB32(t1 + 2, BrB);
          compute(buf);
          if (MODE == 0 && t1 == KT - 1) siluGate();
          if (hn2) vmwait<4 + NB>(); else vmwait<4>();
          writeB32(BrA, buf ^ 1);
          if (hn2) vmwait<NB>(); else vmwait<0>();
          asm volatile("s_waitcnt lgkmcnt(0)" ::: "memory");
          __builtin_amdgcn_s_barrier();
          buf ^= 1;
        } else {
          compute(buf);   // last tile
        }
      }
    }
  }

  // ---- epilogue ----
  #pragma unroll
  for (int m = 0; m < 4; m++) {
    #pragma unroll
    for (int r = 0; r < 4; r++) {
      int lr = wr + m * 16 + lh * 4 + r;
      if (lr >= rows) continue;
      size_t grow = (MODE == 2) ? (size_t)perm[row0 + lr] : (size_t)(row0 + lr);
      size_t base = grow * (size_t)ldc + n0;
      #pragma unroll
      for (int n = 0; n < NREP; n++) {
        int col = wc + n * 16 + l16;
        float v = acc[m][n][r];
        if constexpr (MODE == 0) {
          ((short*)Cv)[base + col] = f2bf(bf2f(sgate[m][n][r]) * v);
        } else if constexpr (MODE == 1) {
          ((float*)Cv)[base + col] = v;
        } else {
          ((float*)Cv)[base + col] += v;
        }
      }
    }
  }
}

// ---------------- launch ----------------
extern "C" void kernel_launch(void* const* d_in, const int* in_sizes, int n_in,
                              void* d_out, int out_size, void* d_ws, size_t ws_size,
                              hipStream_t stream)
{
  const float* h   = (const float*)d_in[0];
  const float* rw  = (const float*)d_in[1];
  const float* gup = (const float*)d_in[2];
  const float* dwn = (const float*)d_in[3];
  const float* sg  = (const float*)d_in[4];
  const float* su  = (const float*)d_in[5];
  const float* sd  = (const float*)d_in[6];
  float* out0   = (float*)d_out;                       // [T, H]
  float* logits = out0 + (size_t)T_TOK * HDIM;         // [T, E]

  char* ws = (char*)d_ws;
  int*   eid    = (int*)ws;                  // 2048 ints
  float* score  = (float*)(ws + 8192);       // 2048 floats
  int*   perm   = (int*)(ws + 16384);        // 2048 ints
  int*   ofs    = (int*)(ws + 24576);        // 9 ints
  short* hb     = (short*)(ws + 32768);                 // [T, H] bf16
  short* xp     = hb  + (size_t)T_TOK * HDIM;           // [T, H] bf16 (perm+scaled)
  short* act_sh = xp  + (size_t)T_TOK * HDIM;           // [T, F] bf16
  short* act_rt = act_sh + (size_t)T_TOK * FDIM;        // [T, F] bf16 (perm space)
  short* sgT    = act_rt + (size_t)T_TOK * FDIM + 8192; // [F, H] bf16 (transposed)
  short* suT    = sgT + (size_t)FDIM * HDIM;            // [F, H] bf16
  short* sdT    = suT + (size_t)FDIM * HDIM;            // [H, F] bf16

  // shared weight conversions (one launch)
  tconv3_kernel<<<dim3(64, 64, 3), 256, 0, stream>>>(sg, su, sd, sgT, suT, sdT);

  router_kernel<<<T_TOK/4, 256, 0, stream>>>(h, rw, logits, eid, score, hb);
  sort_kernel<<<1, 512, 0, stream>>>(eid, perm, ofs);
  build_kernel<<<T_TOK, 256, 0, stream>>>(hb, score, perm, xp);

  const int MT = T_TOK / 128;   // 16
  const int MTR = 4;            // routed mt cap: 512 rows/expert (mean 256±15)

  // shared gate+up fused -> act_sh   (all-bf16, 128x128x64, R6-proven)
  dim3 g_gu_sh(FDIM / 128, MT);
  moe_gemm<0, true, 128, 2><<<g_gu_sh, 256, 0, stream>>>(
      hb, HDIM, sgT, suT, 0, HDIM, act_sh, FDIM, nullptr, MT, HDIM, nullptr);
  // shared down -> out0 (store)      (all-bf16, 128x128x64, R6-proven)
  dim3 g_dn_sh(HDIM / 128, MT);
  moe_gemm<1, true, 128, 2><<<g_dn_sh, 256, 0, stream>>>(
      act_sh, FDIM, sdT, nullptr, 0, FDIM, out0, HDIM, nullptr, MT, FDIM, nullptr);
  // routed gate+up fused (grouped) -> act_rt   (fp32-B deep pipeline, 128x64x64, R10-proven)
  dim3 g_gu_rt(FDIM / 64, NEXP * MTR);
  moe_gemm<0, false, 64, 3><<<g_gu_rt, 256, 0, stream>>>(
      xp, HDIM, gup, gup + FDIM, (long long)HDIM * 2 * FDIM, 2 * FDIM,
      act_rt, FDIM, ofs, MTR, HDIM, nullptr);
  // routed down (grouped, accumulate into out0)  (fp32-B deep pipeline, 128x64x64, R10-proven)
  dim3 g_dn_rt(HDIM / 64, NEXP * MTR);
  moe_gemm<2, false, 64, 3><<<g_dn_rt, 256, 0, stream>>>(
      act_rt, FDIM, dwn, nullptr, (long long)FDIM * HDIM, HDIM,
      out0, HDIM, ofs, MTR, FDIM, perm);
}